// Round 1
// baseline (1021.027 us; speedup 1.0000x reference)
//
#include <hip/hip_runtime.h>
#include <hip/hip_cooperative_groups.h>

namespace cg = cooperative_groups;

#define SENT32 0x7FFFFFFF
#define IDMASK 0x1FFFF
#define RSHIFT 17

__device__ __forceinline__ unsigned fkey(float f) {
    unsigned u = __float_as_uint(f);
    return (u & 0x80000000u) ? ~u : (u | 0x80000000u);
}
__device__ __forceinline__ float funkey(unsigned k) {
    unsigned u = (k & 0x80000000u) ? (k & 0x7FFFFFFFu) : ~k;
    return __uint_as_float(u);
}

// ---- 1. elevation: elev = x @ W + b, f64 accumulation, wave-per-row ----
__global__ __launch_bounds__(256) void k_matvec(const float* __restrict__ x,
                                                const float* __restrict__ W,
                                                const float* __restrict__ b,
                                                double* __restrict__ elev64,
                                                float* __restrict__ elev32,
                                                int N, int C) {
    int lane = threadIdx.x & 63;
    int wib  = threadIdx.x >> 6;
    int row  = blockIdx.x * (blockDim.x >> 6) + wib;
    if (row >= N) return;
    const float* xr = x + (size_t)row * C;
    double s = 0.0;
    for (int c = lane; c < C; c += 64) s += (double)xr[c] * (double)W[c];
#pragma unroll
    for (int off = 32; off > 0; off >>= 1) s += __shfl_down(s, off, 64);
    if (lane == 0) {
        double v = s + (double)b[0];
        elev64[row] = v;
        elev32[row] = (float)v;
    }
}

// ---- 2. edge pass: packed deg/gt/lt counters + compact down-edge list ----
__global__ __launch_bounds__(256) void k_edges(const int* __restrict__ ei,
                                               const double* __restrict__ elev64,
                                               unsigned* __restrict__ cnt,
                                               int2* __restrict__ down,
                                               int* __restrict__ nedown, int E) {
    __shared__ int tmp[256];
    __shared__ int sbase;
    int stride = gridDim.x * blockDim.x;
    for (int e0 = blockIdx.x * blockDim.x; e0 < E; e0 += stride) {
        int e = e0 + threadIdx.x;
        int s = 0, d = 0;
        bool le = false;
        if (e < E) {
            s = ei[e];
            d = ei[(size_t)E + e];
            double es = elev64[s], ed = elev64[d];
            bool ge = (ed >= es);
            le = (ed <= es);
            unsigned pack = (1u << 20) | (ge ? (1u << 10) : 0u) | (le ? 1u : 0u);
            atomicAdd(&cnt[d], pack);
        }
        // block-level compaction of down edges
        tmp[threadIdx.x] = le ? 1 : 0;
        __syncthreads();
        for (int off = 1; off < 256; off <<= 1) {
            int t = (threadIdx.x >= off) ? tmp[threadIdx.x - off] : 0;
            __syncthreads();
            tmp[threadIdx.x] += t;
            __syncthreads();
        }
        int incl = tmp[threadIdx.x];
        int total = tmp[255];
        if (threadIdx.x == 0 && total > 0) sbase = atomicAdd(nedown, total);
        __syncthreads();
        if (le) down[sbase + incl - 1] = make_int2(s, d);
        __syncthreads();
    }
}

// ---- 3. node pass: peak/trough flags, best init, cb init ----
__global__ __launch_bounds__(256) void k_nodes1(const unsigned* __restrict__ cnt,
                                                int* __restrict__ peakflag,
                                                int* __restrict__ best,
                                                float* __restrict__ out_ispeak,
                                                float* __restrict__ out_istrough,
                                                float* __restrict__ out_cb, int N) {
    int n = blockIdx.x * blockDim.x + threadIdx.x;
    if (n >= N) return;
    unsigned c = cnt[n];
    unsigned deg = c >> 20, gt = (c >> 10) & 1023u, lt = c & 1023u;
    int pk = (gt == deg) ? 1 : 0;
    int tr = (lt == deg) ? 1 : 0;
    peakflag[n] = pk;
    out_ispeak[n] = (float)pk;
    out_istrough[n] = (float)tr;
    best[n] = pk ? n : SENT32;
    out_cb[n] = -1.0f;
}

// ---- 4. prefix sum for new_id ----
__global__ __launch_bounds__(256) void k_scan_part(const int* __restrict__ flag,
                                                   int* __restrict__ part, int N) {
    int n = blockIdx.x * 256 + threadIdx.x;
    int f = (n < N) ? flag[n] : 0;
#pragma unroll
    for (int off = 32; off > 0; off >>= 1) f += __shfl_down(f, off, 64);
    __shared__ int ws[4];
    int lane = threadIdx.x & 63, wid = threadIdx.x >> 6;
    if (lane == 0) ws[wid] = f;
    __syncthreads();
    if (threadIdx.x == 0) part[blockIdx.x] = ws[0] + ws[1] + ws[2] + ws[3];
}

__global__ __launch_bounds__(64) void k_scan_offs(const int* __restrict__ part,
                                                  int* __restrict__ offs, int P) {
    int lane = threadIdx.x;
    int chunk = (P + 63) / 64;
    int s0 = lane * chunk, s1 = min(s0 + chunk, P);
    int s = 0;
    for (int j = s0; j < s1; ++j) s += part[j];
    int incl = s;
#pragma unroll
    for (int off = 1; off < 64; off <<= 1) {
        int t = __shfl_up(incl, off, 64);
        if (lane >= off) incl += t;
    }
    int run = incl - s;  // exclusive prefix of this lane's chunk
    for (int j = s0; j < s1; ++j) { offs[j] = run; run += part[j]; }
}

__global__ __launch_bounds__(256) void k_scan_final(const int* __restrict__ flag,
                                                    const int* __restrict__ offs,
                                                    int* __restrict__ new_id, int N) {
    __shared__ int tmp[256];
    int n = blockIdx.x * 256 + threadIdx.x;
    int f = (n < N) ? flag[n] : 0;
    tmp[threadIdx.x] = f;
    __syncthreads();
    for (int off = 1; off < 256; off <<= 1) {
        int t = (threadIdx.x >= off) ? tmp[threadIdx.x - off] : 0;
        __syncthreads();
        tmp[threadIdx.x] += t;
        __syncthreads();
    }
    if (n < N) new_id[n] = offs[blockIdx.x] + tmp[threadIdx.x] - 1;
}

// ---- 5. watershed flood fill, cooperative, synchronous rounds ----
// best[v] packs (round<<17)|peak_id. Readers only accept entries with
// round <= r-1, so same-round atomicMin writes are invisible within a round:
// exact replica of the reference's synchronous segment_min iteration.
__global__ __launch_bounds__(256, 4) void k_flood(const int2* __restrict__ down,
                                                  const int* __restrict__ p_ne,
                                                  int* __restrict__ best,
                                                  int* __restrict__ changed) {
    cg::grid_group grid = cg::this_grid();
    const int ne = *p_ne;
    const int stride = gridDim.x * blockDim.x;
    const int t0 = blockIdx.x * blockDim.x + threadIdx.x;
    for (int r = 1; r < 4096; ++r) {
        const int thr = r << RSHIFT;  // packed values < thr were assigned before round r
        bool any = false;
        for (int e = t0; e < ne; e += stride) {
            int2 ed = down[e];
            int pu = __hip_atomic_load(&best[ed.x], __ATOMIC_RELAXED, __HIP_MEMORY_SCOPE_AGENT);
            if (pu < thr) {  // src assigned by end of round r-1
                int cand = thr | (pu & IDMASK);
                int pv = __hip_atomic_load(&best[ed.y], __ATOMIC_RELAXED, __HIP_MEMORY_SCOPE_AGENT);
                if (pv > cand) {
                    int old = atomicMin(&best[ed.y], cand);
                    if (old > cand) any = true;
                }
            }
        }
        if (any) __hip_atomic_store(&changed[r], 1, __ATOMIC_RELAXED, __HIP_MEMORY_SCOPE_AGENT);
        grid.sync();
        if (__hip_atomic_load(&changed[r], __ATOMIC_RELAXED, __HIP_MEMORY_SCOPE_AGENT) == 0) break;
    }
}

// ---- 6. seg labels, segment max, cluster_batch scatter ----
__global__ __launch_bounds__(256) void k_seg(const int* __restrict__ best,
                                             const int* __restrict__ new_id,
                                             const float* __restrict__ elev32,
                                             const int* __restrict__ batch,
                                             int* __restrict__ seg,
                                             float* __restrict__ out_seg,
                                             unsigned* __restrict__ segmax,
                                             float* __restrict__ out_cb, int N) {
    int n = blockIdx.x * blockDim.x + threadIdx.x;
    if (n >= N) return;
    int a = best[n];
    int sg = 0;
    if (a != SENT32) {
        sg = new_id[a & IDMASK];
        atomicMax(&segmax[sg], fkey(elev32[n]));
        if ((a >> RSHIFT) == 0) out_cb[sg] = (float)batch[n];  // peak node
    }
    seg[n] = sg;
    out_seg[n] = (float)sg;
}

// ---- 7. softmax weights + denominator ----
__global__ __launch_bounds__(256) void k_w(const int* __restrict__ best,
                                           const int* __restrict__ seg,
                                           const float* __restrict__ elev32,
                                           const unsigned* __restrict__ segmax,
                                           float* __restrict__ wbuf,
                                           float* __restrict__ z, int N) {
    int n = blockIdx.x * blockDim.x + threadIdx.x;
    if (n >= N) return;
    int a = best[n];
    int sg = seg[n];
    float wv = 0.0f;
    if (a != SENT32) {
        float smax = funkey(segmax[sg]);
        wv = expf(elev32[n] - smax);
        atomicAdd(&z[sg], wv);
    }
    wbuf[n] = wv;
}

// ---- 8. scaling + weighted pooling (wave-per-node) ----
__global__ __launch_bounds__(256) void k_pool(const float* __restrict__ x,
                                              const int* __restrict__ seg,
                                              const float* __restrict__ wbuf,
                                              const float* __restrict__ z,
                                              float* __restrict__ out_scaling,
                                              float* __restrict__ out_pooled,
                                              int N, int C) {
    int lane = threadIdx.x & 63;
    int node = blockIdx.x * (blockDim.x >> 6) + (threadIdx.x >> 6);
    if (node >= N) return;
    int sg = seg[node];
    float sc = wbuf[node] / (z[sg] + 1e-12f);
    if (lane == 0) out_scaling[node] = sc;
    const float* xr = x + (size_t)node * C;
    float* pr = out_pooled + (size_t)sg * C;
    for (int c = lane; c < C; c += 64) atomicAdd(&pr[c], xr[c] * sc);
}

extern "C" void kernel_launch(void* const* d_in, const int* in_sizes, int n_in,
                              void* d_out, int out_size, void* d_ws, size_t ws_size,
                              hipStream_t stream) {
    const float* x = (const float*)d_in[0];
    const float* W = (const float*)d_in[1];
    const float* b = (const float*)d_in[2];
    const int* ei = (const int*)d_in[3];
    const int* batch = (const int*)d_in[4];

    const int C = in_sizes[1];           // 128
    const int N = in_sizes[0] / C;       // 100000
    const int E = in_sizes[3] / 2;       // 3200000

    float* out_pooled   = (float*)d_out;
    float* out_seg      = out_pooled + (size_t)N * C;
    float* out_scaling  = out_seg + N;
    float* out_cb       = out_scaling + N;
    float* out_ispeak   = out_cb + N;
    float* out_istrough = out_ispeak + N;

    char* p = (char*)d_ws;
    auto alloc = [&](size_t bytes) -> char* {
        char* r = p;
        p += (bytes + 255) & ~(size_t)255;
        return r;
    };
    double* elev64 = (double*)alloc((size_t)N * 8);
    float* elev32  = (float*)alloc((size_t)N * 4);
    int* best      = (int*)alloc((size_t)N * 4);
    int* peakflag  = (int*)alloc((size_t)N * 4);
    int* new_id    = (int*)alloc((size_t)N * 4);
    int* seg       = (int*)alloc((size_t)N * 4);
    float* wbuf    = (float*)alloc((size_t)N * 4);
    const int P = (N + 255) / 256;
    int* part = (int*)alloc((size_t)P * 4);
    int* offs = (int*)alloc((size_t)P * 4);
    char* zbeg = p;  // zero-initialized region starts here
    unsigned* cnt    = (unsigned*)alloc((size_t)N * 4);
    unsigned* segmax = (unsigned*)alloc((size_t)N * 4);
    float* z         = (float*)alloc((size_t)N * 4);
    int* changed     = (int*)alloc(4096 * 4);
    int* nedown      = (int*)alloc(256);
    size_t zspan = (size_t)(p - zbeg);
    int2* down = (int2*)alloc((size_t)E * 8);
    (void)ws_size;

    // zero pooled output region (rest of d_out is fully overwritten below)
    hipMemsetAsync(out_pooled, 0, (size_t)N * C * sizeof(float), stream);
    hipMemsetAsync(zbeg, 0, zspan, stream);

    k_matvec<<<(N + 3) / 4, 256, 0, stream>>>(x, W, b, elev64, elev32, N, C);
    k_edges<<<4096, 256, 0, stream>>>(ei, elev64, cnt, down, nedown, E);
    k_nodes1<<<(N + 255) / 256, 256, 0, stream>>>(cnt, peakflag, best, out_ispeak,
                                                  out_istrough, out_cb, N);
    k_scan_part<<<P, 256, 0, stream>>>(peakflag, part, N);
    k_scan_offs<<<1, 64, 0, stream>>>(part, offs, P);
    k_scan_final<<<P, 256, 0, stream>>>(peakflag, offs, new_id, N);

    void* fargs[] = { (void*)&down, (void*)&nedown, (void*)&best, (void*)&changed };
    hipLaunchCooperativeKernel(k_flood, dim3(512), dim3(256), fargs, 0, stream);

    k_seg<<<(N + 255) / 256, 256, 0, stream>>>(best, new_id, elev32, batch, seg,
                                               out_seg, segmax, out_cb, N);
    k_w<<<(N + 255) / 256, 256, 0, stream>>>(best, seg, elev32, segmax, wbuf, z, N);
    k_pool<<<(N + 3) / 4, 256, 0, stream>>>(x, seg, wbuf, z, out_scaling, out_pooled, N, C);
}

// Round 2
// 939.173 us; speedup vs baseline: 1.0872x; 1.0872x over previous
//
#include <hip/hip_runtime.h>
#include <hip/hip_cooperative_groups.h>

namespace cg = cooperative_groups;

#define SENT32 0x7FFFFFFF
#define IDMASK 0x1FFFF
#define RSHIFT 17

__device__ __forceinline__ unsigned fkey(float f) {
    unsigned u = __float_as_uint(f);
    return (u & 0x80000000u) ? ~u : (u | 0x80000000u);
}
__device__ __forceinline__ float funkey(unsigned k) {
    unsigned u = (k & 0x80000000u) ? (k & 0x7FFFFFFFu) : ~k;
    return __uint_as_float(u);
}

// ---- 1. elevation: elev = x @ W + b, f64 accumulation, wave-per-row ----
__global__ __launch_bounds__(256) void k_matvec(const float* __restrict__ x,
                                                const float* __restrict__ W,
                                                const float* __restrict__ b,
                                                double* __restrict__ elev64,
                                                float* __restrict__ elev32,
                                                int N, int C) {
    int lane = threadIdx.x & 63;
    int wib  = threadIdx.x >> 6;
    int row  = blockIdx.x * (blockDim.x >> 6) + wib;
    if (row >= N) return;
    const float* xr = x + (size_t)row * C;
    double s = 0.0;
    for (int c = lane; c < C; c += 64) s += (double)xr[c] * (double)W[c];
#pragma unroll
    for (int off = 32; off > 0; off >>= 1) s += __shfl_down(s, off, 64);
    if (lane == 0) {
        double v = s + (double)b[0];
        elev64[row] = v;
        elev32[row] = (float)v;
    }
}

// ---- 2a. edge pass A: packed deg/gt/lt counters + down out-degree ----
__global__ __launch_bounds__(256) void k_edgeA(const int* __restrict__ ei,
                                               const double* __restrict__ elev64,
                                               unsigned* __restrict__ cnt,
                                               int* __restrict__ odeg, int E) {
    int e = blockIdx.x * blockDim.x + threadIdx.x;
    if (e >= E) return;
    int s = ei[e];
    int d = ei[(size_t)E + e];
    double es = elev64[s], ed = elev64[d];
    bool ge = (ed >= es);
    bool le = (ed <= es);
    unsigned pack = (1u << 20) | (ge ? (1u << 10) : 0u) | (le ? 1u : 0u);
    atomicAdd(&cnt[d], pack);
    if (le) atomicAdd(&odeg[s], 1);
}

// ---- 2b. edge pass B: CSR adjacency fill (down edges, grouped by src) ----
__global__ __launch_bounds__(256) void k_fill(const int* __restrict__ ei,
                                              const double* __restrict__ elev64,
                                              int* __restrict__ cursor,
                                              int* __restrict__ adj, int E) {
    int e = blockIdx.x * blockDim.x + threadIdx.x;
    if (e >= E) return;
    int s = ei[e];
    int d = ei[(size_t)E + e];
    if (elev64[d] <= elev64[s]) {
        int pos = atomicAdd(&cursor[s], 1);
        adj[pos] = d;
    }
}

// ---- 3. node pass: peak/trough flags, best init, initial frontier ----
__global__ __launch_bounds__(256) void k_nodes1(const unsigned* __restrict__ cnt,
                                                int* __restrict__ peakflag,
                                                int* __restrict__ best,
                                                float* __restrict__ out_ispeak,
                                                float* __restrict__ out_istrough,
                                                float* __restrict__ out_cb,
                                                int* __restrict__ fcnt,
                                                int* __restrict__ fb0, int N) {
    int n = blockIdx.x * blockDim.x + threadIdx.x;
    if (n >= N) return;
    unsigned c = cnt[n];
    unsigned deg = c >> 20, gt = (c >> 10) & 1023u, lt = c & 1023u;
    int pk = (gt == deg) ? 1 : 0;
    int tr = (lt == deg) ? 1 : 0;
    peakflag[n] = pk;
    out_ispeak[n] = (float)pk;
    out_istrough[n] = (float)tr;
    best[n] = pk ? n : SENT32;
    out_cb[n] = -1.0f;
    if (pk) {
        int pos = atomicAdd(&fcnt[0], 1);
        fb0[pos] = n;
    }
}

// ---- 4. prefix sums (new_id over peakflag; rowptr over odeg) ----
__global__ __launch_bounds__(256) void k_scan_part(const int* __restrict__ flag,
                                                   int* __restrict__ part, int N) {
    int n = blockIdx.x * 256 + threadIdx.x;
    int f = (n < N) ? flag[n] : 0;
#pragma unroll
    for (int off = 32; off > 0; off >>= 1) f += __shfl_down(f, off, 64);
    __shared__ int ws[4];
    int lane = threadIdx.x & 63, wid = threadIdx.x >> 6;
    if (lane == 0) ws[wid] = f;
    __syncthreads();
    if (threadIdx.x == 0) part[blockIdx.x] = ws[0] + ws[1] + ws[2] + ws[3];
}

__global__ __launch_bounds__(64) void k_scan_offs(const int* __restrict__ part,
                                                  int* __restrict__ offs, int P) {
    int lane = threadIdx.x;
    int chunk = (P + 63) / 64;
    int s0 = lane * chunk, s1 = min(s0 + chunk, P);
    int s = 0;
    for (int j = s0; j < s1; ++j) s += part[j];
    int incl = s;
#pragma unroll
    for (int off = 1; off < 64; off <<= 1) {
        int t = __shfl_up(incl, off, 64);
        if (lane >= off) incl += t;
    }
    int run = incl - s;  // exclusive prefix of this lane's chunk
    for (int j = s0; j < s1; ++j) { offs[j] = run; run += part[j]; }
}

// mode 0: out0[n] = inclusive-1        (new_id)
// mode 1: out0[n] = exclusive, out1[n] = exclusive  (rowptr + cursor)
__global__ __launch_bounds__(256) void k_scan_final(const int* __restrict__ flag,
                                                    const int* __restrict__ offs,
                                                    int* __restrict__ out0,
                                                    int* __restrict__ out1,
                                                    int mode, int N) {
    __shared__ int tmp[256];
    int n = blockIdx.x * 256 + threadIdx.x;
    int f = (n < N) ? flag[n] : 0;
    tmp[threadIdx.x] = f;
    __syncthreads();
    for (int off = 1; off < 256; off <<= 1) {
        int t = (threadIdx.x >= off) ? tmp[threadIdx.x - off] : 0;
        __syncthreads();
        tmp[threadIdx.x] += t;
        __syncthreads();
    }
    if (n < N) {
        int incl = offs[blockIdx.x] + tmp[threadIdx.x];
        if (mode == 0) {
            out0[n] = incl - 1;
        } else {
            int excl = incl - f;
            out0[n] = excl;
            out1[n] = excl;
        }
    }
}

// ---- 5. watershed flood fill: frontier BFS, synchronous rounds ----
// best[v] packs (round<<17)|peak_id. Frontier level L holds nodes assigned
// at round L; their down-edges are processed exactly once (at round L+1),
// atomicMin reproduces segment_min, first-writer (old==SENT) appends v.
__global__ __launch_bounds__(256, 4) void k_flood(const int* __restrict__ rowptr,
                                                  const int* __restrict__ odeg,
                                                  const int* __restrict__ adj,
                                                  int* __restrict__ best,
                                                  int* __restrict__ fcnt,
                                                  int* __restrict__ fb0,
                                                  int* __restrict__ fb1) {
    cg::grid_group grid = cg::this_grid();
    const int stride = gridDim.x * blockDim.x;
    const int t0 = blockIdx.x * blockDim.x + threadIdx.x;
    for (int L = 0; L < 8190; ++L) {
        int n = __hip_atomic_load(&fcnt[L], __ATOMIC_RELAXED, __HIP_MEMORY_SCOPE_AGENT);
        if (n == 0) break;
        const int* cur = (L & 1) ? fb1 : fb0;
        int* nxt = (L & 1) ? fb0 : fb1;
        const int thr = (L + 1) << RSHIFT;
        for (int i = t0; i < n; i += stride) {
            int u = cur[i];
            int pu = __hip_atomic_load(&best[u], __ATOMIC_RELAXED, __HIP_MEMORY_SCOPE_AGENT);
            int cand = thr | (pu & IDMASK);
            int a = rowptr[u];
            int m = odeg[u];
            for (int j = 0; j < m; ++j) {
                int v = adj[a + j];
                int pv = __hip_atomic_load(&best[v], __ATOMIC_RELAXED, __HIP_MEMORY_SCOPE_AGENT);
                if (pv > cand) {
                    int old = atomicMin(&best[v], cand);
                    if (old == SENT32) {
                        int pos = atomicAdd(&fcnt[L + 1], 1);
                        nxt[pos] = v;
                    }
                }
            }
        }
        grid.sync();
    }
}

// ---- 6. seg labels, segment max, cluster_batch scatter ----
__global__ __launch_bounds__(256) void k_seg(const int* __restrict__ best,
                                             const int* __restrict__ new_id,
                                             const float* __restrict__ elev32,
                                             const int* __restrict__ batch,
                                             int* __restrict__ seg,
                                             float* __restrict__ out_seg,
                                             unsigned* __restrict__ segmax,
                                             float* __restrict__ out_cb, int N) {
    int n = blockIdx.x * blockDim.x + threadIdx.x;
    if (n >= N) return;
    int a = best[n];
    int sg = 0;
    if (a != SENT32) {
        sg = new_id[a & IDMASK];
        atomicMax(&segmax[sg], fkey(elev32[n]));
        if ((a >> RSHIFT) == 0) out_cb[sg] = (float)batch[n];  // peak node
    }
    seg[n] = sg;
    out_seg[n] = (float)sg;
}

// ---- 7. softmax weights + denominator ----
__global__ __launch_bounds__(256) void k_w(const int* __restrict__ best,
                                           const int* __restrict__ seg,
                                           const float* __restrict__ elev32,
                                           const unsigned* __restrict__ segmax,
                                           float* __restrict__ wbuf,
                                           float* __restrict__ z, int N) {
    int n = blockIdx.x * blockDim.x + threadIdx.x;
    if (n >= N) return;
    int a = best[n];
    int sg = seg[n];
    float wv = 0.0f;
    if (a != SENT32) {
        float smax = funkey(segmax[sg]);
        wv = expf(elev32[n] - smax);
        atomicAdd(&z[sg], wv);
    }
    wbuf[n] = wv;
}

// ---- 8. scaling + weighted pooling (wave-per-node) ----
__global__ __launch_bounds__(256) void k_pool(const float* __restrict__ x,
                                              const int* __restrict__ seg,
                                              const float* __restrict__ wbuf,
                                              const float* __restrict__ z,
                                              float* __restrict__ out_scaling,
                                              float* __restrict__ out_pooled,
                                              int N, int C) {
    int lane = threadIdx.x & 63;
    int node = blockIdx.x * (blockDim.x >> 6) + (threadIdx.x >> 6);
    if (node >= N) return;
    int sg = seg[node];
    float sc = wbuf[node] / (z[sg] + 1e-12f);
    if (lane == 0) out_scaling[node] = sc;
    const float* xr = x + (size_t)node * C;
    float* pr = out_pooled + (size_t)sg * C;
    for (int c = lane; c < C; c += 64) atomicAdd(&pr[c], xr[c] * sc);
}

extern "C" void kernel_launch(void* const* d_in, const int* in_sizes, int n_in,
                              void* d_out, int out_size, void* d_ws, size_t ws_size,
                              hipStream_t stream) {
    const float* x = (const float*)d_in[0];
    const float* W = (const float*)d_in[1];
    const float* b = (const float*)d_in[2];
    const int* ei = (const int*)d_in[3];
    const int* batch = (const int*)d_in[4];

    const int C = in_sizes[1];           // 128
    const int N = in_sizes[0] / C;       // 100000
    const int E = in_sizes[3] / 2;       // 3200000

    float* out_pooled   = (float*)d_out;
    float* out_seg      = out_pooled + (size_t)N * C;
    float* out_scaling  = out_seg + N;
    float* out_cb       = out_scaling + N;
    float* out_ispeak   = out_cb + N;
    float* out_istrough = out_ispeak + N;

    char* p = (char*)d_ws;
    auto alloc = [&](size_t bytes) -> char* {
        char* r = p;
        p += (bytes + 255) & ~(size_t)255;
        return r;
    };
    double* elev64 = (double*)alloc((size_t)N * 8);
    float* elev32  = (float*)alloc((size_t)N * 4);
    int* best      = (int*)alloc((size_t)N * 4);
    int* peakflag  = (int*)alloc((size_t)N * 4);
    int* new_id    = (int*)alloc((size_t)N * 4);
    int* seg       = (int*)alloc((size_t)N * 4);
    float* wbuf    = (float*)alloc((size_t)N * 4);
    int* rowptr    = (int*)alloc((size_t)N * 4);
    int* cursor    = (int*)alloc((size_t)N * 4);
    int* fb0       = (int*)alloc((size_t)N * 4);
    int* fb1       = (int*)alloc((size_t)N * 4);
    const int P = (N + 255) / 256;
    int* part = (int*)alloc((size_t)P * 4);
    int* offs = (int*)alloc((size_t)P * 4);
    char* zbeg = p;  // zero-initialized region starts here
    unsigned* cnt    = (unsigned*)alloc((size_t)N * 4);
    unsigned* segmax = (unsigned*)alloc((size_t)N * 4);
    float* z         = (float*)alloc((size_t)N * 4);
    int* odeg        = (int*)alloc((size_t)N * 4);
    int* fcnt        = (int*)alloc(8192 * 4);
    size_t zspan = (size_t)(p - zbeg);
    int* adj = (int*)alloc((size_t)E * 4);
    (void)ws_size;

    hipMemsetAsync(out_pooled, 0, (size_t)N * C * sizeof(float), stream);
    hipMemsetAsync(zbeg, 0, zspan, stream);

    k_matvec<<<(N + 3) / 4, 256, 0, stream>>>(x, W, b, elev64, elev32, N, C);
    k_edgeA<<<(E + 255) / 256, 256, 0, stream>>>(ei, elev64, cnt, odeg, E);
    k_nodes1<<<(N + 255) / 256, 256, 0, stream>>>(cnt, peakflag, best, out_ispeak,
                                                  out_istrough, out_cb, fcnt, fb0, N);
    // new_id = inclusive_scan(peakflag) - 1
    k_scan_part<<<P, 256, 0, stream>>>(peakflag, part, N);
    k_scan_offs<<<1, 64, 0, stream>>>(part, offs, P);
    k_scan_final<<<P, 256, 0, stream>>>(peakflag, offs, new_id, nullptr, 0, N);
    // rowptr/cursor = exclusive_scan(odeg)
    k_scan_part<<<P, 256, 0, stream>>>(odeg, part, N);
    k_scan_offs<<<1, 64, 0, stream>>>(part, offs, P);
    k_scan_final<<<P, 256, 0, stream>>>(odeg, offs, rowptr, cursor, 1, N);

    k_fill<<<(E + 255) / 256, 256, 0, stream>>>(ei, elev64, cursor, adj, E);

    void* fargs[] = { (void*)&rowptr, (void*)&odeg, (void*)&adj, (void*)&best,
                      (void*)&fcnt, (void*)&fb0, (void*)&fb1 };
    hipLaunchCooperativeKernel(k_flood, dim3(256), dim3(256), fargs, 0, stream);

    k_seg<<<(N + 255) / 256, 256, 0, stream>>>(best, new_id, elev32, batch, seg,
                                               out_seg, segmax, out_cb, N);
    k_w<<<(N + 255) / 256, 256, 0, stream>>>(best, seg, elev32, segmax, wbuf, z, N);
    k_pool<<<(N + 3) / 4, 256, 0, stream>>>(x, seg, wbuf, z, out_scaling, out_pooled, N, C);
}